// Round 9
// baseline (481.168 us; speedup 1.0000x reference)
//
#include <hip/hip_runtime.h>
#include <hip/hip_bf16.h>
#include <hip/hip_cooperative_groups.h>

namespace cg = cooperative_groups;

// GNN forward: 3 layers of COO SpMM + gating, mean over layer embeddings.
// N=50000, E=800000, D=96.
//
// Round-13: cooperative single-launch fusion of the whole pipeline.
//  Evidence: r10/r11 (ELL write coalescing) regressed, r12 (bucket_cnt
//  padding) null -> all in-kernel theories for the ~60us non-spmm budget are
//  dead. Remaining untouched cost: dispatch structure itself (6 graph nodes:
//  memset + 5 kernels; ~1.5-3us gap/drain each + idle chip during the
//  196-block ell_build). Fix: ONE hipLaunchCooperativeKernel, grid.sync()
//  between phases, grid-stride loops; grid sized by occupancy query (no
//  deadlock); runtime fallback to the r12 multi-launch path if coop launch
//  is rejected. Phase bodies byte-identical to r12.

#define N_NODES 50000
#define N_EDGES 800000
#define EMB 96
#define C16 12                    // 16B bf16 chunks per row
#define TPR 6                     // threads per row (2 chunks each)
#define LAYER_NUM 3
#define PAD 64                    // ELL slots per row
#define NCHUNK (N_NODES * C16)    // 600000 bf16 chunks total

#define NBUCK 196                 // ceil(50000/256) coarse buckets (row>>8)
#define RPB 256                   // rows per bucket
#define CAP 5000                  // record capacity per bucket
#define CNT_PAD 16                // ints per counter: one 64B line each
#define EDGE_BLOCKS 782           // ceil(200000 quad-edges / 256)
#define CONV_BLOCKS 2344          // ceil(600000 chunks / 256)
#define VB_SETUP (EDGE_BLOCKS + CONV_BLOCKS)
#define VB_SPMM ((N_NODES * TPR + 255) / 256)   // 1172

__device__ __forceinline__ float bflo(unsigned u) { return __uint_as_float(u << 16); }
__device__ __forceinline__ float bfhi(unsigned u) { return __uint_as_float(u & 0xffff0000u); }

__device__ __forceinline__ void fma_bf8(float* s, float v, const uint4& u) {
    s[0] = fmaf(v, bflo(u.x), s[0]);
    s[1] = fmaf(v, bfhi(u.x), s[1]);
    s[2] = fmaf(v, bflo(u.y), s[2]);
    s[3] = fmaf(v, bfhi(u.y), s[3]);
    s[4] = fmaf(v, bflo(u.z), s[4]);
    s[5] = fmaf(v, bfhi(u.z), s[5]);
    s[6] = fmaf(v, bflo(u.w), s[6]);
    s[7] = fmaf(v, bfhi(u.w), s[7]);
}

__device__ __forceinline__ void unpack8(float* d, const uint4& u) {
    d[0] = bflo(u.x); d[1] = bfhi(u.x);
    d[2] = bflo(u.y); d[3] = bfhi(u.y);
    d[4] = bflo(u.z); d[5] = bfhi(u.z);
    d[6] = bflo(u.w); d[7] = bfhi(u.w);
}

// RNE pack: a -> low 16, b -> high 16
__device__ __forceinline__ unsigned packbf(float a, float b) {
    unsigned ua = __float_as_uint(a);
    unsigned ub = __float_as_uint(b);
    ua = (ua + 0x7fffu + ((ua >> 16) & 1u)) >> 16;
    ub = (ub + 0x7fffu + ((ub >> 16) & 1u)) & 0xffff0000u;
    return ua | ub;
}

// ---------------- phase device functions (shared by coop + fallback) ------

// Setup virtual-block vb: edge binning or X->bf16 convert.
__device__ void setup_vb(int vb, int tid,
                         const float4* __restrict__ X4,
                         uint4* __restrict__ Xb,
                         const int4* __restrict__ rows4,
                         const int4* __restrict__ cols4,
                         const float4* __restrict__ vals4,
                         int* __restrict__ bucket_cnt,
                         uint2* __restrict__ bucket_buf,
                         int* hist, int* gbase) {
    if (vb < EDGE_BLOCKS) {
        for (int i = tid; i < NBUCK; i += 256) hist[i] = 0;
        __syncthreads();

        int e = vb * 256 + tid;                  // quad-edge index
        bool act = (e < N_EDGES / 4);
        int4 r, c; float4 v;
        int b0 = 0, b1 = 0, b2 = 0, b3 = 0;
        int k0 = 0, k1 = 0, k2 = 0, k3 = 0;
        if (act) {
            r = rows4[e]; c = cols4[e]; v = vals4[e];
            b0 = r.x >> 8; b1 = r.y >> 8; b2 = r.z >> 8; b3 = r.w >> 8;
            k0 = atomicAdd(&hist[b0], 1);        // LDS atomics: no fabric
            k1 = atomicAdd(&hist[b1], 1);
            k2 = atomicAdd(&hist[b2], 1);
            k3 = atomicAdd(&hist[b3], 1);
        }
        __syncthreads();

        for (int i = tid; i < NBUCK; i += 256)
            gbase[i] = atomicAdd(&bucket_cnt[i * CNT_PAD], hist[i]);
        __syncthreads();

        if (act) {
            uint2 p;
            int d;
            d = gbase[b0] + k0;
            if (d < CAP) {
                p.x = (unsigned)c.x | ((unsigned)(r.x & 255) << 24);
                p.y = __float_as_uint(v.x);
                bucket_buf[b0 * CAP + d] = p;
            }
            d = gbase[b1] + k1;
            if (d < CAP) {
                p.x = (unsigned)c.y | ((unsigned)(r.y & 255) << 24);
                p.y = __float_as_uint(v.y);
                bucket_buf[b1 * CAP + d] = p;
            }
            d = gbase[b2] + k2;
            if (d < CAP) {
                p.x = (unsigned)c.z | ((unsigned)(r.z & 255) << 24);
                p.y = __float_as_uint(v.z);
                bucket_buf[b2 * CAP + d] = p;
            }
            d = gbase[b3] + k3;
            if (d < CAP) {
                p.x = (unsigned)c.w | ((unsigned)(r.w & 255) << 24);
                p.y = __float_as_uint(v.w);
                bucket_buf[b3 * CAP + d] = p;
            }
        }
        __syncthreads();                         // protect hist reuse
    } else {
        int chunk = (vb - EDGE_BLOCKS) * 256 + tid;
        if (chunk < NCHUNK) {
            float4 a = X4[chunk * 2];
            float4 b = X4[chunk * 2 + 1];
            uint4 o;
            o.x = packbf(a.x, a.y);
            o.y = packbf(a.z, a.w);
            o.z = packbf(b.x, b.y);
            o.w = packbf(b.z, b.w);
            Xb[chunk] = o;
        }
    }
}

// ELL build for one bucket (256-thread block).
__device__ void ellbuild_vb(int b, int tid,
                            const int* __restrict__ bucket_cnt,
                            const uint2* __restrict__ bucket_buf,
                            int2* __restrict__ ell,
                            int* __restrict__ cnt,
                            int* lc) {
    lc[tid] = 0;                                  // RPB == blockDim == 256
    __syncthreads();

    int n = bucket_cnt[b * CNT_PAD];
    if (n > CAP) n = CAP;
    const uint2* buf = bucket_buf + b * CAP;
    for (int i = tid; i < n; i += 256) {
        uint2 rec = buf[i];
        int rl = rec.x >> 24;
        int slot = atomicAdd(&lc[rl], 1);         // LDS atomic
        if (slot < PAD) {
            int2 p;
            p.x = (int)(rec.x & 0x00ffffffu);
            p.y = (int)rec.y;
            ell[(b * RPB + rl) * PAD + slot] = p;
        }
    }
    __syncthreads();
    int row = b * RPB + tid;
    if (row < N_NODES) {
        int d = lc[tid];
        cnt[row] = (d > PAD) ? PAD : d;
    }
    __syncthreads();                              // protect lc reuse
}

// SpMM for one thread-task t in [0, N_NODES*TPR).
// MODE 0: ego_out = agg*(1+ego_in). MODE 1: acc = (Xb+e1+ego_in+e3)*0.25.
template <int MODE>
__device__ void spmm_task(int t,
                          const uint4* __restrict__ ego_in,
                          uint4* __restrict__ ego_out,
                          const int* __restrict__ cnt,
                          const int4* __restrict__ ell4,
                          const uint4* __restrict__ xb,
                          const uint4* __restrict__ e1v,
                          float4* __restrict__ acc) {
    int row = t / TPR;
    int ct  = t % TPR;

    int deg = cnt[row];
    const int4* ep = ell4 + row * (PAD / 2);

    float s0[8] = {0.f, 0.f, 0.f, 0.f, 0.f, 0.f, 0.f, 0.f};
    float s1[8] = {0.f, 0.f, 0.f, 0.f, 0.f, 0.f, 0.f, 0.f};

    int j = 0;
    for (; j + 4 <= deg; j += 4) {
        int4 pA = ep[j >> 1];
        int4 pB = ep[(j >> 1) + 1];
        const uint4* b0 = ego_in + pA.x * C16;
        const uint4* b1 = ego_in + pA.z * C16;
        const uint4* b2 = ego_in + pB.x * C16;
        const uint4* b3 = ego_in + pB.z * C16;
        uint4 x0a = b0[ct], x0b = b0[ct + TPR];
        uint4 x1a = b1[ct], x1b = b1[ct + TPR];
        uint4 x2a = b2[ct], x2b = b2[ct + TPR];
        uint4 x3a = b3[ct], x3b = b3[ct + TPR];
        float v0 = __int_as_float(pA.y);
        float v1 = __int_as_float(pA.w);
        float v2 = __int_as_float(pB.y);
        float v3 = __int_as_float(pB.w);
        fma_bf8(s0, v0, x0a); fma_bf8(s1, v0, x0b);
        fma_bf8(s0, v1, x1a); fma_bf8(s1, v1, x1b);
        fma_bf8(s0, v2, x2a); fma_bf8(s1, v2, x2b);
        fma_bf8(s0, v3, x3a); fma_bf8(s1, v3, x3b);
    }
    for (; j + 2 <= deg; j += 2) {
        int4 pA = ep[j >> 1];
        const uint4* b0 = ego_in + pA.x * C16;
        const uint4* b1 = ego_in + pA.z * C16;
        uint4 x0a = b0[ct], x0b = b0[ct + TPR];
        uint4 x1a = b1[ct], x1b = b1[ct + TPR];
        float v0 = __int_as_float(pA.y);
        float v1 = __int_as_float(pA.w);
        fma_bf8(s0, v0, x0a); fma_bf8(s1, v0, x0b);
        fma_bf8(s0, v1, x1a); fma_bf8(s1, v1, x1b);
    }
    if (j < deg) {
        int2 p = ((const int2*)ell4)[row * PAD + j];
        const uint4* b0 = ego_in + p.x * C16;
        uint4 x0a = b0[ct], x0b = b0[ct + TPR];
        float v0 = __int_as_float(p.y);
        fma_bf8(s0, v0, x0a); fma_bf8(s1, v0, x0b);
    }

    int ib = row * C16 + ct;
    uint4 ea = ego_in[ib];
    uint4 eb = ego_in[ib + TPR];
    float e0[8], e1[8];
    unpack8(e0, ea);
    unpack8(e1, eb);
    float n0[8], n1[8];
#pragma unroll
    for (int k = 0; k < 8; ++k) {
        n0[k] = fmaf(s0[k], e0[k], s0[k]);   // s*(1+e)
        n1[k] = fmaf(s1[k], e1[k], s1[k]);
    }

    if (MODE == 0) {
        uint4 oa, ob;
        oa.x = packbf(n0[0], n0[1]); oa.y = packbf(n0[2], n0[3]);
        oa.z = packbf(n0[4], n0[5]); oa.w = packbf(n0[6], n0[7]);
        ob.x = packbf(n1[0], n1[1]); ob.y = packbf(n1[2], n1[3]);
        ob.z = packbf(n1[4], n1[5]); ob.w = packbf(n1[6], n1[7]);
        ego_out[ib]       = oa;
        ego_out[ib + TPR] = ob;
    } else {
        float x0[8], x1[8], f0[8], f1[8];
        unpack8(x0, xb[ib]);
        unpack8(x1, xb[ib + TPR]);
        unpack8(f0, e1v[ib]);
        unpack8(f1, e1v[ib + TPR]);
        int ia = row * (EMB / 4) + ct * 2;
        float4 a0, a1, a2, a3;
        a0.x = (x0[0] + f0[0] + e0[0] + n0[0]) * 0.25f;
        a0.y = (x0[1] + f0[1] + e0[1] + n0[1]) * 0.25f;
        a0.z = (x0[2] + f0[2] + e0[2] + n0[2]) * 0.25f;
        a0.w = (x0[3] + f0[3] + e0[3] + n0[3]) * 0.25f;
        a1.x = (x0[4] + f0[4] + e0[4] + n0[4]) * 0.25f;
        a1.y = (x0[5] + f0[5] + e0[5] + n0[5]) * 0.25f;
        a1.z = (x0[6] + f0[6] + e0[6] + n0[6]) * 0.25f;
        a1.w = (x0[7] + f0[7] + e0[7] + n0[7]) * 0.25f;
        a2.x = (x1[0] + f1[0] + e1[0] + n1[0]) * 0.25f;
        a2.y = (x1[1] + f1[1] + e1[1] + n1[1]) * 0.25f;
        a2.z = (x1[2] + f1[2] + e1[2] + n1[2]) * 0.25f;
        a2.w = (x1[3] + f1[3] + e1[3] + n1[3]) * 0.25f;
        a3.x = (x1[4] + f1[4] + e1[4] + n1[4]) * 0.25f;
        a3.y = (x1[5] + f1[5] + e1[5] + n1[5]) * 0.25f;
        a3.z = (x1[6] + f1[6] + e1[6] + n1[6]) * 0.25f;
        a3.w = (x1[7] + f1[7] + e1[7] + n1[7]) * 0.25f;
        acc[ia]      = a0;
        acc[ia + 1]  = a1;
        acc[ia + 12] = a2;
        acc[ia + 13] = a3;
    }
}

// ---------------- cooperative mega-kernel ---------------------------------

__global__ void fused_kernel(const float4* __restrict__ X4,
                             uint4* __restrict__ Xb,
                             const int4* __restrict__ rows4,
                             const int4* __restrict__ cols4,
                             const float4* __restrict__ vals4,
                             int* __restrict__ bucket_cnt,
                             uint2* __restrict__ bucket_buf,
                             int2* __restrict__ ell,
                             int* __restrict__ cnt,
                             uint4* __restrict__ ego_a,
                             uint4* __restrict__ ego_b,
                             float4* __restrict__ acc) {
    cg::grid_group grid = cg::this_grid();
    __shared__ int hist[NBUCK];
    __shared__ int gbase[NBUCK];
    __shared__ int lc[RPB];

    const int tid = threadIdx.x;
    const int nb  = gridDim.x;

    // phase 0: zero bucket counters (replaces the memset dispatch)
    for (int i = blockIdx.x * 256 + tid; i < NBUCK * CNT_PAD; i += nb * 256)
        bucket_cnt[i] = 0;
    grid.sync();

    // phase 1: convert + edge binning
    for (int vb = blockIdx.x; vb < VB_SETUP; vb += nb)
        setup_vb(vb, tid, X4, Xb, rows4, cols4, vals4, bucket_cnt, bucket_buf,
                 hist, gbase);
    grid.sync();

    // phase 2: ELL build
    for (int b = blockIdx.x; b < NBUCK; b += nb)
        ellbuild_vb(b, tid, bucket_cnt, bucket_buf, ell, cnt, lc);
    grid.sync();

    // phase 3-5: spmm layers
    for (int t = blockIdx.x * 256 + tid; t < N_NODES * TPR; t += nb * 256)
        spmm_task<0>(t, Xb, ego_a, cnt, (const int4*)ell, nullptr, nullptr, nullptr);
    grid.sync();
    for (int t = blockIdx.x * 256 + tid; t < N_NODES * TPR; t += nb * 256)
        spmm_task<0>(t, ego_a, ego_b, cnt, (const int4*)ell, nullptr, nullptr, nullptr);
    grid.sync();
    for (int t = blockIdx.x * 256 + tid; t < N_NODES * TPR; t += nb * 256)
        spmm_task<1>(t, ego_b, nullptr, cnt, (const int4*)ell, Xb, ego_a, acc);
}

// ---------------- fallback standalone kernels (r12 path) ------------------

__global__ void setup_kernel(const float4* __restrict__ X4,
                             uint4* __restrict__ Xb,
                             const int4* __restrict__ rows4,
                             const int4* __restrict__ cols4,
                             const float4* __restrict__ vals4,
                             int* __restrict__ bucket_cnt,
                             uint2* __restrict__ bucket_buf) {
    __shared__ int hist[NBUCK];
    __shared__ int gbase[NBUCK];
    setup_vb(blockIdx.x, threadIdx.x, X4, Xb, rows4, cols4, vals4,
             bucket_cnt, bucket_buf, hist, gbase);
}

__global__ void ell_build_kernel(const int* __restrict__ bucket_cnt,
                                 const uint2* __restrict__ bucket_buf,
                                 int2* __restrict__ ell,
                                 int* __restrict__ cnt) {
    __shared__ int lc[RPB];
    ellbuild_vb(blockIdx.x, threadIdx.x, bucket_cnt, bucket_buf, ell, cnt, lc);
}

template <int MODE>
__global__ void spmm_fused_kernel(const uint4* __restrict__ ego_in,
                                  uint4* __restrict__ ego_out,
                                  const int* __restrict__ cnt,
                                  const int4* __restrict__ ell4,
                                  const uint4* __restrict__ xb,
                                  const uint4* __restrict__ e1v,
                                  float4* __restrict__ acc) {
    int t = blockIdx.x * blockDim.x + threadIdx.x;
    if (t < N_NODES * TPR)
        spmm_task<MODE>(t, ego_in, ego_out, cnt, ell4, xb, e1v, acc);
}

extern "C" void kernel_launch(void* const* d_in, const int* in_sizes, int n_in,
                              void* d_out, int out_size, void* d_ws, size_t ws_size,
                              hipStream_t stream) {
    const float4* X4    = (const float4*)d_in[0];
    const float4* vals4 = (const float4*)d_in[1];
    const int4*   rows4 = (const int4*)d_in[2];
    const int4*   cols4 = (const int4*)d_in[3];

    const size_t nodeb_bytes = (size_t)NCHUNK * sizeof(uint4);       // 9.6 MB
    const size_t ell_bytes   = (size_t)N_NODES * PAD * sizeof(int2); // 25.6 MB
    const size_t cnt_bytes   = (size_t)N_NODES * sizeof(int);        // 0.2 MB

    float4* acc = (float4*)d_out;

    char* w = (char*)d_ws;
    uint4* Xb    = (uint4*)w;  w += nodeb_bytes;   // bf16 node rows (AoS, 192B)
    uint4* ego_a = (uint4*)w;  w += nodeb_bytes;   // e1
    uint4* ego_b = (uint4*)w;  w += nodeb_bytes;   // e2
    int2*  ell   = (int2*)w;   w += ell_bytes;
    int*   cnt   = (int*)w;    w += cnt_bytes;

    // bucket scratch aliases ego_a/ego_b: consumed before spmm writes them
    uint2* bucket_buf = (uint2*)ego_a;             // 196*5000*8 = 7.84 MB
    int*   bucket_cnt = (int*)ego_b;               // 12.5 KB

    // co-residency-safe cooperative grid (cached across calls)
    static int coopGrid = -1;
    if (coopGrid < 0) {
        int occ = 0;
        if (hipOccupancyMaxActiveBlocksPerMultiprocessor(&occ, fused_kernel,
                                                         256, 0) != hipSuccess)
            occ = 0;
        if (occ < 1) {
            coopGrid = 0;                          // no safe coop config
        } else {
            long g = (long)occ * 256;              // 256 CUs on MI355X
            if (g > VB_SPMM) g = VB_SPMM;
            coopGrid = (int)g;
        }
    }

    hipError_t err = hipErrorUnknown;
    if (coopGrid > 0) {
        void* args[] = {
            (void*)&X4, (void*)&Xb, (void*)&rows4, (void*)&cols4, (void*)&vals4,
            (void*)&bucket_cnt, (void*)&bucket_buf, (void*)&ell, (void*)&cnt,
            (void*)&ego_a, (void*)&ego_b, (void*)&acc
        };
        err = hipLaunchCooperativeKernel((const void*)fused_kernel,
                                         dim3(coopGrid), dim3(256),
                                         args, 0, stream);
    }

    if (err != hipSuccess) {
        // fallback: r12 multi-launch path (190.1us-class)
        hipMemsetAsync(bucket_cnt, 0, NBUCK * CNT_PAD * sizeof(int), stream);
        setup_kernel<<<VB_SETUP, 256, 0, stream>>>(
            X4, Xb, rows4, cols4, vals4, bucket_cnt, bucket_buf);
        ell_build_kernel<<<NBUCK, 256, 0, stream>>>(bucket_cnt, bucket_buf, ell, cnt);
        spmm_fused_kernel<0><<<VB_SPMM, 256, 0, stream>>>(
            Xb, ego_a, cnt, (const int4*)ell, nullptr, nullptr, nullptr);
        spmm_fused_kernel<0><<<VB_SPMM, 256, 0, stream>>>(
            ego_a, ego_b, cnt, (const int4*)ell, nullptr, nullptr, nullptr);
        spmm_fused_kernel<1><<<VB_SPMM, 256, 0, stream>>>(
            ego_b, nullptr, cnt, (const int4*)ell, Xb, ego_a, acc);
    }
}

// Round 12
// 173.854 us; speedup vs baseline: 2.7676x; 2.7676x over previous
//
#include <hip/hip_runtime.h>
#include <hip/hip_bf16.h>

// GNN forward: 3 layers of COO SpMM + gating, mean over layer embeddings.
// N=50000, E=800000, D=96.
//
// Round-16: resubmit of round-15 (infra died twice; kernel audited clean —
// workspace 67.4MB < r14's 69.4MB which ran, indices in-bounds, grids
// identical in form to verified r12).
//  r15 theory: group-quantized int8 gather tables (2 lines/row).
//  fp8 (r14) failed precision at 7168/2703 — e4m3 = 32x bf16 rounding +
//  scale saturation. Same sector-reduction lever, safer rung: 16 int8
//  mantissas + shared bf16 scale per group (one group per gather thread).
//  Row = 96B mantissa + 12B scales in a 128B stride = 2 lines/edge (vs
//  bf16's 3). Error ~ 0.4% of group max ~ bf16-class. Gathers only;
//  self/gating/acc stay bf16/fp32; ELL exact (col, f32 val).
//  Encode: scale = groupmax/127 * 1.0078 margin, RNE to bf16, clamp +-127,
//  zero-guard. Decode: (int)(w<<k)>>24 + cvt + fma, coef = val*scale.
//  q8 ping-pong: setup->X8(q8a); L1 reads q8a writes e1(q8b); L2 reads q8b
//  writes e2(q8a); L3 reads q8a. Everything else = r12 (190us best).

#define N_NODES 50000
#define N_EDGES 800000
#define EMB 96
#define C16 12                    // 16B bf16 chunks per row
#define TPR 6                     // threads per row
#define PAD 64                    // ELL slots per row
#define NCHUNK (N_NODES * C16)
#define Q8U4 8                    // uint4 per q8 row (128B stride)

#define NBUCK 196                 // ceil(50000/256) coarse buckets (row>>8)
#define RPB 256                   // rows per bucket
#define CAP 5000                  // record capacity per bucket
#define CNT_PAD 16                // bucket counters: one 64B line each
#define EDGE_BLOCKS 782           // ceil(200000 quad-edges / 256)
#define CONV_BLOCKS ((N_NODES * TPR + 255) / 256)   // 1172
#define VB_SETUP (EDGE_BLOCKS + CONV_BLOCKS)
#define VB_SPMM ((N_NODES * TPR + 255) / 256)

__device__ __forceinline__ float bflo(unsigned u) { return __uint_as_float(u << 16); }
__device__ __forceinline__ float bfhi(unsigned u) { return __uint_as_float(u & 0xffff0000u); }

__device__ __forceinline__ void unpack8(float* d, const uint4& u) {
    d[0] = bflo(u.x); d[1] = bfhi(u.x);
    d[2] = bflo(u.y); d[3] = bfhi(u.y);
    d[4] = bflo(u.z); d[5] = bfhi(u.z);
    d[6] = bflo(u.w); d[7] = bfhi(u.w);
}

// RNE pack: a -> low 16, b -> high 16
__device__ __forceinline__ unsigned packbf(float a, float b) {
    unsigned ua = __float_as_uint(a);
    unsigned ub = __float_as_uint(b);
    ua = (ua + 0x7fffu + ((ua >> 16) & 1u)) >> 16;
    ub = (ub + 0x7fffu + ((ub >> 16) & 1u)) & 0xffff0000u;
    return ua | ub;
}

// ---- group int8 encode: 16 feats -> 1 uint4 mantissas + bf16 scale -------
__device__ __forceinline__ unsigned q8w(const int* m) {
    return (unsigned)(m[0] & 255) | ((unsigned)(m[1] & 255) << 8) |
           ((unsigned)(m[2] & 255) << 16) | ((unsigned)(m[3] & 255) << 24);
}

__device__ __forceinline__ void q8enc(const float* f, uint4* mout,
                                      unsigned short* sout) {
    float mx = 0.f;
#pragma unroll
    for (int k = 0; k < 16; ++k) mx = fmaxf(mx, fabsf(f[k]));
    unsigned sb = 0;
    float inv = 0.f;
    if (mx > 1e-30f) {
        float sc = mx * (1.0078125f / 127.0f);   // margin covers bf16 RNE-down
        unsigned u = __float_as_uint(sc);
        sb = (u + 0x7fffu + ((u >> 16) & 1u)) >> 16;
        inv = 1.0f / __uint_as_float(sb << 16);
    }
    int m[16];
#pragma unroll
    for (int k = 0; k < 16; ++k) {
        int v = __float2int_rn(f[k] * inv);
        m[k] = min(127, max(-127, v));
    }
    uint4 o;
    o.x = q8w(m); o.y = q8w(m + 4); o.z = q8w(m + 8); o.w = q8w(m + 12);
    *mout = o;
    *sout = (unsigned short)sb;
}

// ---- group int8 decode-accumulate ----------------------------------------
__device__ __forceinline__ void fma_q8x4(float* s, float c, unsigned w) {
    s[0] = fmaf(c, (float)((int)(w << 24) >> 24), s[0]);
    s[1] = fmaf(c, (float)((int)(w << 16) >> 24), s[1]);
    s[2] = fmaf(c, (float)((int)(w << 8) >> 24), s[2]);
    s[3] = fmaf(c, (float)((int)w >> 24), s[3]);
}

__device__ __forceinline__ void fma_q8x16(float* s, float c, const uint4& x) {
    fma_q8x4(s,      c, x.x);
    fma_q8x4(s + 4,  c, x.y);
    fma_q8x4(s + 8,  c, x.z);
    fma_q8x4(s + 12, c, x.w);
}

// q8 row layout (128B stride): bytes [ct*16..ct*16+15] = mantissas of thread
// ct's 16 feats {8ct..8ct+7, 8ct+48..8ct+55}; bytes [96+2ct] = bf16 scale.

// K1: blocks [0, EDGE_BLOCKS): bin 1024 edges each into coarse buckets.
//     blocks [EDGE_BLOCKS, VB_SETUP): X fp32 -> bf16 AoS + q8 rows.
__global__ void setup_kernel(const float4* __restrict__ X4,
                             uint4* __restrict__ Xb,
                             uint4* __restrict__ Xq8,
                             const int4* __restrict__ rows4,
                             const int4* __restrict__ cols4,
                             const float4* __restrict__ vals4,
                             int* __restrict__ bucket_cnt,
                             uint2* __restrict__ bucket_buf) {
    __shared__ int hist[NBUCK];
    __shared__ int gbase[NBUCK];
    int tid = threadIdx.x;

    if (blockIdx.x < EDGE_BLOCKS) {
        for (int i = tid; i < NBUCK; i += 256) hist[i] = 0;
        __syncthreads();

        int e = blockIdx.x * 256 + tid;          // quad-edge index
        bool act = (e < N_EDGES / 4);
        int4 r, c; float4 v;
        int b0 = 0, b1 = 0, b2 = 0, b3 = 0;
        int k0 = 0, k1 = 0, k2 = 0, k3 = 0;
        if (act) {
            r = rows4[e]; c = cols4[e]; v = vals4[e];
            b0 = r.x >> 8; b1 = r.y >> 8; b2 = r.z >> 8; b3 = r.w >> 8;
            k0 = atomicAdd(&hist[b0], 1);        // LDS atomics: no fabric
            k1 = atomicAdd(&hist[b1], 1);
            k2 = atomicAdd(&hist[b2], 1);
            k3 = atomicAdd(&hist[b3], 1);
        }
        __syncthreads();

        for (int i = tid; i < NBUCK; i += 256)
            gbase[i] = atomicAdd(&bucket_cnt[i * CNT_PAD], hist[i]);
        __syncthreads();

        if (act) {
            uint2 p;
            int d;
            d = gbase[b0] + k0;
            if (d < CAP) {
                p.x = (unsigned)c.x | ((unsigned)(r.x & 255) << 24);
                p.y = __float_as_uint(v.x);
                bucket_buf[b0 * CAP + d] = p;
            }
            d = gbase[b1] + k1;
            if (d < CAP) {
                p.x = (unsigned)c.y | ((unsigned)(r.y & 255) << 24);
                p.y = __float_as_uint(v.y);
                bucket_buf[b1 * CAP + d] = p;
            }
            d = gbase[b2] + k2;
            if (d < CAP) {
                p.x = (unsigned)c.z | ((unsigned)(r.z & 255) << 24);
                p.y = __float_as_uint(v.z);
                bucket_buf[b2 * CAP + d] = p;
            }
            d = gbase[b3] + k3;
            if (d < CAP) {
                p.x = (unsigned)c.w | ((unsigned)(r.w & 255) << 24);
                p.y = __float_as_uint(v.w);
                bucket_buf[b3 * CAP + d] = p;
            }
        }
    } else {
        int th = (blockIdx.x - EDGE_BLOCKS) * 256 + tid;
        if (th < N_NODES * TPR) {
            int row = th / TPR;
            int ct  = th % TPR;
            const float4* Xr = X4 + row * 24;
            float4 a = Xr[2 * ct];
            float4 b = Xr[2 * ct + 1];
            float4 c = Xr[2 * ct + 12];
            float4 d = Xr[2 * ct + 13];
            uint4 oa, ob;
            oa.x = packbf(a.x, a.y); oa.y = packbf(a.z, a.w);
            oa.z = packbf(b.x, b.y); oa.w = packbf(b.z, b.w);
            ob.x = packbf(c.x, c.y); ob.y = packbf(c.z, c.w);
            ob.z = packbf(d.x, d.y); ob.w = packbf(d.z, d.w);
            Xb[row * C16 + ct]       = oa;
            Xb[row * C16 + ct + TPR] = ob;
            float f[16] = {a.x, a.y, a.z, a.w, b.x, b.y, b.z, b.w,
                           c.x, c.y, c.z, c.w, d.x, d.y, d.z, d.w};
            unsigned short sb;
            uint4 mq;
            q8enc(f, &mq, &sb);
            Xq8[row * Q8U4 + ct] = mq;
            ((unsigned short*)Xq8)[row * 64 + 48 + ct] = sb;
        }
    }
}

// K2: one block (512 thr) per bucket. LDS slot counters; writes in 128KB
// window; emits compact cnt[row]. (r12 form — r10/11 LDS staging regressed.)
__global__ void ell_build_kernel(const int* __restrict__ bucket_cnt,
                                 const uint2* __restrict__ bucket_buf,
                                 int2* __restrict__ ell,
                                 int* __restrict__ cnt) {
    __shared__ int lc[RPB];
    int b = blockIdx.x;
    int tid = threadIdx.x;
    if (tid < RPB) lc[tid] = 0;
    __syncthreads();

    int n = bucket_cnt[b * CNT_PAD];
    if (n > CAP) n = CAP;
    const uint2* buf = bucket_buf + b * CAP;
    for (int i = tid; i < n; i += 512) {
        uint2 rec = buf[i];
        int rl = rec.x >> 24;
        int slot = atomicAdd(&lc[rl], 1);        // LDS atomic
        if (slot < PAD) {
            int2 p;
            p.x = (int)(rec.x & 0x00ffffffu);
            p.y = (int)rec.y;
            ell[(b * RPB + rl) * PAD + slot] = p;
        }
    }
    __syncthreads();
    if (tid < RPB) {
        int row = b * RPB + tid;
        if (row < N_NODES) {
            int d = lc[tid];
            cnt[row] = (d > PAD) ? PAD : d;
        }
    }
}

// One thread per (row, ct). Gathers q8 rows: 1 uint4 + 1 ushort per edge
// (2 lines/edge). Self/gating/acc stay bf16/fp32.
// MODE 0: ego_out(bf16) + q8_out. MODE 1: acc = (Xb+e1+ego_in+e3)*0.25.
template <int MODE>
__global__ void spmm_fused_kernel(const uint4* __restrict__ ego_in,
                                  const uint4* __restrict__ q8_in,
                                  uint4* __restrict__ ego_out,
                                  uint4* __restrict__ q8_out,
                                  const int* __restrict__ cnt,
                                  const int4* __restrict__ ell4,
                                  const uint4* __restrict__ xb,
                                  const uint4* __restrict__ e1v,
                                  float4* __restrict__ acc) {
    int tid = blockIdx.x * blockDim.x + threadIdx.x;
    if (tid >= N_NODES * TPR) return;
    int row = tid / TPR;
    int ct  = tid % TPR;

    int deg = cnt[row];
    const int4* ep = ell4 + row * (PAD / 2);
    const unsigned short* qs = (const unsigned short*)q8_in;

    float s[16] = {0.f, 0.f, 0.f, 0.f, 0.f, 0.f, 0.f, 0.f,
                   0.f, 0.f, 0.f, 0.f, 0.f, 0.f, 0.f, 0.f};

    int j = 0;
    for (; j + 4 <= deg; j += 4) {
        int4 pA = ep[j >> 1];
        int4 pB = ep[(j >> 1) + 1];
        uint4 x0 = q8_in[pA.x * Q8U4 + ct];
        uint4 x1 = q8_in[pA.z * Q8U4 + ct];
        uint4 x2 = q8_in[pB.x * Q8U4 + ct];
        uint4 x3 = q8_in[pB.z * Q8U4 + ct];
        float c0 = __int_as_float(pA.y) * bflo((unsigned)qs[pA.x * 64 + 48 + ct]);
        float c1 = __int_as_float(pA.w) * bflo((unsigned)qs[pA.z * 64 + 48 + ct]);
        float c2 = __int_as_float(pB.y) * bflo((unsigned)qs[pB.x * 64 + 48 + ct]);
        float c3 = __int_as_float(pB.w) * bflo((unsigned)qs[pB.z * 64 + 48 + ct]);
        fma_q8x16(s, c0, x0);
        fma_q8x16(s, c1, x1);
        fma_q8x16(s, c2, x2);
        fma_q8x16(s, c3, x3);
    }
    for (; j + 2 <= deg; j += 2) {
        int4 pA = ep[j >> 1];
        uint4 x0 = q8_in[pA.x * Q8U4 + ct];
        uint4 x1 = q8_in[pA.z * Q8U4 + ct];
        float c0 = __int_as_float(pA.y) * bflo((unsigned)qs[pA.x * 64 + 48 + ct]);
        float c1 = __int_as_float(pA.w) * bflo((unsigned)qs[pA.z * 64 + 48 + ct]);
        fma_q8x16(s, c0, x0);
        fma_q8x16(s, c1, x1);
    }
    if (j < deg) {
        int2 p = ((const int2*)ell4)[row * PAD + j];
        uint4 x0 = q8_in[p.x * Q8U4 + ct];
        float c0 = __int_as_float(p.y) * bflo((unsigned)qs[p.x * 64 + 48 + ct]);
        fma_q8x16(s, c0, x0);
    }

    int ib = row * C16 + ct;
    uint4 ea = ego_in[ib];
    uint4 eb = ego_in[ib + TPR];
    float e0[8], e1[8];
    unpack8(e0, ea);
    unpack8(e1, eb);
    float n0[8], n1[8];
#pragma unroll
    for (int k = 0; k < 8; ++k) {
        n0[k] = fmaf(s[k],     e0[k], s[k]);     // s*(1+e)
        n1[k] = fmaf(s[8 + k], e1[k], s[8 + k]);
    }

    if (MODE == 0) {
        uint4 oa, ob;
        oa.x = packbf(n0[0], n0[1]); oa.y = packbf(n0[2], n0[3]);
        oa.z = packbf(n0[4], n0[5]); oa.w = packbf(n0[6], n0[7]);
        ob.x = packbf(n1[0], n1[1]); ob.y = packbf(n1[2], n1[3]);
        ob.z = packbf(n1[4], n1[5]); ob.w = packbf(n1[6], n1[7]);
        ego_out[ib]       = oa;
        ego_out[ib + TPR] = ob;
        float f[16] = {n0[0], n0[1], n0[2], n0[3], n0[4], n0[5], n0[6], n0[7],
                       n1[0], n1[1], n1[2], n1[3], n1[4], n1[5], n1[6], n1[7]};
        unsigned short sb;
        uint4 mq;
        q8enc(f, &mq, &sb);
        q8_out[row * Q8U4 + ct] = mq;
        ((unsigned short*)q8_out)[row * 64 + 48 + ct] = sb;
    } else {
        // acc = (X + e1 + e2 + e3) / 4 ; ego_in is e2 (bf16), n is e3
        float x0[8], x1[8], f0[8], f1[8];
        unpack8(x0, xb[ib]);
        unpack8(x1, xb[ib + TPR]);
        unpack8(f0, e1v[ib]);
        unpack8(f1, e1v[ib + TPR]);
        int ia = row * (EMB / 4) + ct * 2;   // chunks 2ct, 2ct+1, 2ct+12, 2ct+13
        float4 a0, a1, a2, a3;
        a0.x = (x0[0] + f0[0] + e0[0] + n0[0]) * 0.25f;
        a0.y = (x0[1] + f0[1] + e0[1] + n0[1]) * 0.25f;
        a0.z = (x0[2] + f0[2] + e0[2] + n0[2]) * 0.25f;
        a0.w = (x0[3] + f0[3] + e0[3] + n0[3]) * 0.25f;
        a1.x = (x0[4] + f0[4] + e0[4] + n0[4]) * 0.25f;
        a1.y = (x0[5] + f0[5] + e0[5] + n0[5]) * 0.25f;
        a1.z = (x0[6] + f0[6] + e0[6] + n0[6]) * 0.25f;
        a1.w = (x0[7] + f0[7] + e0[7] + n0[7]) * 0.25f;
        a2.x = (x1[0] + f1[0] + e1[0] + n1[0]) * 0.25f;
        a2.y = (x1[1] + f1[1] + e1[1] + n1[1]) * 0.25f;
        a2.z = (x1[2] + f1[2] + e1[2] + n1[2]) * 0.25f;
        a2.w = (x1[3] + f1[3] + e1[3] + n1[3]) * 0.25f;
        a3.x = (x1[4] + f1[4] + e1[4] + n1[4]) * 0.25f;
        a3.y = (x1[5] + f1[5] + e1[5] + n1[5]) * 0.25f;
        a3.z = (x1[6] + f1[6] + e1[6] + n1[6]) * 0.25f;
        a3.w = (x1[7] + f1[7] + e1[7] + n1[7]) * 0.25f;
        acc[ia]      = a0;
        acc[ia + 1]  = a1;
        acc[ia + 12] = a2;
        acc[ia + 13] = a3;
    }
}

extern "C" void kernel_launch(void* const* d_in, const int* in_sizes, int n_in,
                              void* d_out, int out_size, void* d_ws, size_t ws_size,
                              hipStream_t stream) {
    const float* X    = (const float*)d_in[0];
    const float* vals = (const float*)d_in[1];
    const int*   rows = (const int*)d_in[2];
    const int*   cols = (const int*)d_in[3];

    const size_t nodeb_bytes = (size_t)NCHUNK * sizeof(uint4);        // 9.6 MB
    const size_t q8_bytes    = (size_t)N_NODES * Q8U4 * sizeof(uint4); // 6.4 MB
    const size_t ell_bytes   = (size_t)N_NODES * PAD * sizeof(int2);  // 25.6 MB
    const size_t cnt_bytes   = 204800;                                // 0.2 MB

    float* acc = (float*)d_out;

    char* w = (char*)d_ws;
    uint4* Xb    = (uint4*)w;  w += nodeb_bytes;   // bf16 node rows (AoS, 192B)
    uint4* ego_a = (uint4*)w;  w += nodeb_bytes;   // e1 bf16
    uint4* ego_b = (uint4*)w;  w += nodeb_bytes;   // e2 bf16
    int2*  ell   = (int2*)w;   w += ell_bytes;
    int*   cnt   = (int*)w;    w += cnt_bytes;
    uint4* q8a   = (uint4*)w;  w += q8_bytes;      // X q8, then e2 q8
    uint4* q8b   = (uint4*)w;  w += q8_bytes;      // e1 q8

    // bucket scratch aliases ego_a/ego_b: consumed by K2 before spmm writes them
    uint2* bucket_buf = (uint2*)ego_a;             // 7.84 MB <= 9.6 MB
    int*   bucket_cnt = (int*)ego_b;               // 12.5 KB

    hipMemsetAsync(bucket_cnt, 0, NBUCK * CNT_PAD * sizeof(int), stream);

    setup_kernel<<<VB_SETUP, 256, 0, stream>>>(
        (const float4*)X, Xb, q8a,
        (const int4*)rows, (const int4*)cols, (const float4*)vals,
        bucket_cnt, bucket_buf);

    ell_build_kernel<<<NBUCK, 512, 0, stream>>>(bucket_cnt, bucket_buf, ell, cnt);

    // layer 1: gathers X q8 (q8a), writes e1 bf16 + e1 q8 (q8b)
    spmm_fused_kernel<0><<<VB_SPMM, 256, 0, stream>>>(
        Xb, q8a, ego_a, q8b, cnt, (const int4*)ell, nullptr, nullptr, nullptr);
    // layer 2: gathers e1 q8 (q8b), writes e2 bf16 + e2 q8 (q8a)
    spmm_fused_kernel<0><<<VB_SPMM, 256, 0, stream>>>(
        ego_a, q8b, ego_b, q8a, cnt, (const int4*)ell, nullptr, nullptr, nullptr);
    // layer 3: gathers e2 q8 (q8a), acc = (X + e1 + e2 + e3)/4
    spmm_fused_kernel<1><<<VB_SPMM, 256, 0, stream>>>(
        ego_b, q8a, nullptr, nullptr, cnt, (const int4*)ell, Xb, ego_a,
        (float4*)acc);
}